// Round 8
// baseline (3257.122 us; speedup 1.0000x reference)
//
#include <hip/hip_runtime.h>
#include <hip/hip_bf16.h>
#include <hip/hip_fp16.h>

#define HDIM 1024
#define BATCH 64
#define SEQ 2048
#define MTOT (BATCH*SEQ)   // 131072
#define BM 128
#define BN 128
#define BK 64
#define NKT (HDIM/BK)      // 16 k-tiles

typedef float f32x4 __attribute__((ext_vector_type(4)));
typedef _Float16 half8 __attribute__((ext_vector_type(8)));

static __device__ __forceinline__ void gload_lds16(const void* g, void* l) {
  __builtin_amdgcn_global_load_lds((const __attribute__((address_space(1))) void*)g,
                                   (__attribute__((address_space(3))) void*)l, 16, 0, 0);
}

// ---------------- kernel 1: W1 [h][k] fp32 -> W1T [k][h] fp16 ----------------
__global__ void k_w1t(const float* __restrict__ W1, unsigned short* __restrict__ W1T) {
  __shared__ float tile[64][65];
  int h0 = blockIdx.x * 64, k0 = blockIdx.y * 64;
  int t = threadIdx.x;
#pragma unroll
  for (int j = 0; j < 4; ++j) {
    int q = j * 256 + t, r = q >> 4, c = (q & 15) * 4;
    float4 v = *(const float4*)(W1 + (size_t)(h0 + r) * HDIM + k0 + c);
    tile[r][c + 0] = v.x; tile[r][c + 1] = v.y; tile[r][c + 2] = v.z; tile[r][c + 3] = v.w;
  }
  __syncthreads();
#pragma unroll
  for (int j = 0; j < 4; ++j) {
    int q = j * 256 + t, r = q >> 4, c = (q & 15) * 4;
    union { _Float16 h[4]; ushort4 u; } cv;
    cv.h[0] = (_Float16)tile[c + 0][r];
    cv.h[1] = (_Float16)tile[c + 1][r];
    cv.h[2] = (_Float16)tile[c + 2][r];
    cv.h[3] = (_Float16)tile[c + 3][r];
    *(ushort4*)(W1T + (size_t)(k0 + r) * HDIM + h0 + c) = cv.u;
  }
}

// ---------------- kernel 2: dec_proj = dh @ W2 + b  (fp32) ----------------
__global__ void k_decproj(const float* __restrict__ dh, const float* __restrict__ W2,
                          const float* __restrict__ W2b, float* __restrict__ dp) {
  __shared__ float drow[HDIM];
  int b = blockIdx.x, t = threadIdx.x;
#pragma unroll
  for (int j = 0; j < 4; ++j) drow[j * 256 + t] = dh[(size_t)b * HDIM + j * 256 + t];
  __syncthreads();
  f32x4 acc = {0.f, 0.f, 0.f, 0.f};
#pragma unroll 16
  for (int h = 0; h < HDIM; ++h) {
    float d = drow[h];
    f32x4 w = *(const f32x4*)(W2 + (size_t)h * HDIM + t * 4);
    acc += w * d;
  }
  acc += *(const f32x4*)(W2b + t * 4);
  *(f32x4*)(dp + (size_t)b * HDIM + t * 4) = acc;
}

// ---------------- kernel 3: fused GEMM + tanh + v-dot -> score partials ----------------
// R6 body verbatim; LDS trimmed to EXACTLY 32768 B (As+Bs only; scr aliased onto
// As, bias/v in registers) -> 5 blocks/CU (was 3). Occupancy is the remaining
// lever on R6's ~60% no-issue stall: 5 independent blocks interleave their
// barrier/load phases per CU.
__global__ __launch_bounds__(256, 5) void k_scores(
    const float* __restrict__ E, const unsigned short* __restrict__ W1T,
    const float* __restrict__ W1b, const float* __restrict__ dp,
    const float* __restrict__ vw, float* __restrict__ spart) {
  __shared__ __align__(16) _Float16 As[BM * BK];         // 16384 B, swizzled
  __shared__ __align__(16) unsigned short Bs[BN * BK];   // 16384 B, swizzled
  float (*scr)[2] = (float(*)[2])As;                     // epilogue alias (post-barrier safe)

  int t = threadIdx.x;
  // XCD-aware remap: all 8 n-tiles of an m-tile adjacent on one XCD (FETCH 2.1G->0.33G, R2).
  int bid = blockIdx.x;                 // 0..8191
  int xcd = bid & 7;
  int q = bid >> 3;
  int mt = (xcd << 7) + (q >> 3);
  int nt = q & 7;
  int m0 = mt * BM, n0 = nt * BN;
  int b = m0 >> 11;

  int lane = t & 63, wid = t >> 6;
  int wr = wid >> 1, wc = wid & 1;
  int l15 = lane & 15, l4 = lane >> 4;

  // bias + v for this lane's 4 output columns — registers, no LDS
  float bias_l[4], v_l[4];
#pragma unroll
  for (int ni = 0; ni < 4; ++ni) {
    int k = n0 + wc * 64 + ni * 16 + l15;
    bias_l[ni] = W1b[k] + dp[(size_t)b * HDIM + k];
    v_l[ni] = vw[k];
  }

  f32x4 acc[4][4];
#pragma unroll
  for (int i = 0; i < 4; ++i)
#pragma unroll
    for (int j = 0; j < 4; ++j) acc[i][j] = {0.f, 0.f, 0.f, 0.f};

  // A staging coords: thread covers rows j*16+ar (j=0..7), fp32 cols ac..ac+3
  int ar = t >> 4;                       // 0..15 ; row&7 == ar&7 for all j
  int ac = (t & 15) * 4;                 // 0..60
  int aswz = (((ac >> 3) ^ (ar & 7)) << 4) + ((ac & 7) << 1);
  const float* Ab = E + (size_t)m0 * HDIM;

  // prologue: A(0) -> regs
  float4 areg[8];
#pragma unroll
  for (int j = 0; j < 8; ++j)
    areg[j] = *(const float4*)(Ab + (size_t)(j * 16 + ar) * HDIM + ac);

  for (int kt = 0; kt < NKT; ++kt) {
    // (1) issue B(kt): 4 gload_lds per wave, pre-swizzled source.
#pragma unroll
    for (int j = 0; j < 4; ++j) {
      int chunk = wid * 4 + j;
      int row = chunk * 8 + (lane >> 3);           // row&7 == lane>>3
      int u = (lane & 7) ^ (lane >> 3);
      const unsigned short* g = W1T + (size_t)(n0 + row) * HDIM + kt * BK + u * 8;
      gload_lds16(g, (char*)Bs + (size_t)chunk * 1024);
    }

    // (2) cvt A(kt) regs -> fp16 -> swizzled LDS
#pragma unroll
    for (int j = 0; j < 8; ++j) {
      union { _Float16 h[4]; unsigned long long u64; } cv;
      cv.h[0] = (_Float16)areg[j].x; cv.h[1] = (_Float16)areg[j].y;
      cv.h[2] = (_Float16)areg[j].z; cv.h[3] = (_Float16)areg[j].w;
      *(unsigned long long*)((char*)As + (j * 16 + ar) * 128 + aswz) = cv.u64;
    }

    __syncthreads();   // drains B gloads + A ds_writes

    // (3) prefetch A(kt+1) -> regs; latency hides under MFMA below
    int ktn = ((kt + 1) & (NKT - 1)) * BK;
#pragma unroll
    for (int j = 0; j < 8; ++j)
      areg[j] = *(const float4*)(Ab + (size_t)(j * 16 + ar) * HDIM + ktn + ac);

    // (4) fragments + MFMA (swizzled reads: 0 conflicts — R6 verified)
    __builtin_amdgcn_s_setprio(1);
#pragma unroll
    for (int ks = 0; ks < 2; ++ks) {
      half8 af[4], bf[4];
#pragma unroll
      for (int mi = 0; mi < 4; ++mi) {
        int row = wr * 64 + mi * 16 + l15;
        af[mi] = *(const half8*)((const char*)As + row * 128 + (((ks * 4 + l4) ^ (row & 7)) << 4));
      }
#pragma unroll
      for (int ni = 0; ni < 4; ++ni) {
        int row = wc * 64 + ni * 16 + l15;
        bf[ni] = *(const half8*)((const char*)Bs + row * 128 + (((ks * 4 + l4) ^ (row & 7)) << 4));
      }
#pragma unroll
      for (int mi = 0; mi < 4; ++mi)
#pragma unroll
        for (int ni = 0; ni < 4; ++ni)
          acc[mi][ni] = __builtin_amdgcn_mfma_f32_16x16x32_f16(af[mi], bf[ni], acc[mi][ni], 0, 0, 0);
    }
    __builtin_amdgcn_s_setprio(0);

    __syncthreads();   // LDS reads done before next iter overwrites
  }

  // epilogue: bias + tanh + v-dot, 16-lane shuffle reduce, cross-wc via scr(=As)
#pragma unroll
  for (int mi = 0; mi < 4; ++mi) {
#pragma unroll
    for (int r = 0; r < 4; ++r) {
      float s = 0.f;
#pragma unroll
      for (int ni = 0; ni < 4; ++ni) {
        float x = acc[mi][ni][r] + bias_l[ni];
        float ex = __expf(2.f * x);
        float th = 1.f - 2.f / (ex + 1.f);
        s += th * v_l[ni];
      }
      s += __shfl_xor(s, 1); s += __shfl_xor(s, 2);
      s += __shfl_xor(s, 4); s += __shfl_xor(s, 8);
      if (l15 == 0) scr[wr * 64 + mi * 16 + l4 * 4 + r][wc] = s;
    }
  }
  __syncthreads();
  if (t < BM) spart[((size_t)m0 + t) * 8 + nt] = scr[t][0] + scr[t][1];
}

// ---------------- kernel 4: softmax over S per batch ----------------
__global__ void k_softmax(const float* __restrict__ spart, float* __restrict__ attn) {
  __shared__ float sc[SEQ];
  __shared__ float red[8];
  int b = blockIdx.x, t = threadIdx.x;
  float mx = -1e30f;
#pragma unroll
  for (int j = 0; j < 8; ++j) {
    int s = j * 256 + t;
    const f32x4* p = (const f32x4*)(spart + ((size_t)b * SEQ + s) * 8);
    f32x4 x = p[0], y = p[1];
    float v = (x[0] + x[1]) + (x[2] + x[3]) + (y[0] + y[1]) + (y[2] + y[3]);
    sc[s] = v;
    mx = fmaxf(mx, v);
  }
  for (int m = 1; m < 64; m <<= 1) mx = fmaxf(mx, __shfl_xor(mx, m));
  if ((t & 63) == 0) red[t >> 6] = mx;
  __syncthreads();
  mx = fmaxf(fmaxf(red[0], red[1]), fmaxf(red[2], red[3]));
  float w[8]; float sum = 0.f;
#pragma unroll
  for (int j = 0; j < 8; ++j) {
    float e = __expf(sc[j * 256 + t] - mx);
    w[j] = e; sum += e;
  }
  for (int m = 1; m < 64; m <<= 1) sum += __shfl_xor(sum, m);
  if ((t & 63) == 0) red[4 + (t >> 6)] = sum;
  __syncthreads();
  float inv = 1.f / (red[4] + red[5] + red[6] + red[7]);
#pragma unroll
  for (int j = 0; j < 8; ++j)
    attn[(size_t)b * SEQ + j * 256 + t] = w[j] * inv;
}

// ---------------- kernel 5: context partials over s-chunks ----------------
__global__ void k_ctx_part(const float* __restrict__ E, const float* __restrict__ attn,
                           float* __restrict__ cpart, int rpc) {
  int b = blockIdx.y, ch = blockIdx.x, nch = gridDim.x;
  int t = threadIdx.x;
  const float* wrow = attn + (size_t)b * SEQ + (size_t)ch * rpc;
  const float* Eb = E + ((size_t)b * SEQ + (size_t)ch * rpc) * HDIM;
  f32x4 acc = {0.f, 0.f, 0.f, 0.f};
#pragma unroll 4
  for (int s = 0; s < rpc; ++s) {
    float w = wrow[s];
    f32x4 e = *(const f32x4*)(Eb + (size_t)s * HDIM + t * 4);
    acc += e * w;
  }
  *(f32x4*)(cpart + ((size_t)b * nch + ch) * HDIM + t * 4) = acc;
}

// ---------------- kernel 6: reduce context partials ----------------
__global__ void k_ctx_reduce(const float* __restrict__ cpart, float* __restrict__ ctx, int nch) {
  int idx = blockIdx.x * 256 + threadIdx.x;  // 0..65535
  int b = idx >> 10, k = idx & 1023;
  float s = 0.f;
  for (int c = 0; c < nch; ++c) s += cpart[((size_t)(b * nch + c)) * HDIM + k];
  ctx[idx] = s;
}

extern "C" void kernel_launch(void* const* d_in, const int* in_sizes, int n_in,
                              void* d_out, int out_size, void* d_ws, size_t ws_size,
                              hipStream_t stream) {
  const float* dh  = (const float*)d_in[0];
  const float* E   = (const float*)d_in[1];
  const float* W1w = (const float*)d_in[2];
  const float* W1b = (const float*)d_in[3];
  const float* W2w = (const float*)d_in[4];
  const float* W2b = (const float*)d_in[5];
  const float* vw  = (const float*)d_in[6];
  float* out  = (float*)d_out;
  float* ctx  = out;                 // [64,1024]
  float* attn = out + BATCH * HDIM;  // [64,2048]

  char* ws = (char*)d_ws;
  unsigned short* W1T = (unsigned short*)ws;                 // 2 MB
  float* dp    = (float*)(ws + (2u << 20));                  // 256 KB
  float* spart = (float*)(ws + (2u << 20) + (256u << 10));   // 4 MB
  float* cpart = (float*)(ws + (6u << 20) + (256u << 10));   // up to 8 MB

  size_t need32 = (6u << 20) + (256u << 10) + (size_t)BATCH * 32 * HDIM * 4;
  int nch = (ws_size >= need32) ? 32 : 16;
  int rpc = SEQ / nch;

  k_w1t<<<dim3(16, 16), 256, 0, stream>>>(W1w, W1T);
  k_decproj<<<BATCH, 256, 0, stream>>>(dh, W2w, W2b, dp);
  k_scores<<<(MTOT / BM) * (HDIM / BN), 256, 0, stream>>>(E, W1T, W1b, dp, vw, spart);
  k_softmax<<<BATCH, 256, 0, stream>>>(spart, attn);
  k_ctx_part<<<dim3(nch, BATCH), 256, 0, stream>>>(E, attn, cpart, rpc);
  k_ctx_reduce<<<256, 256, 0, stream>>>(cpart, ctx, nch);
}

// Round 9
// 1182.157 us; speedup vs baseline: 2.7552x; 2.7552x over previous
//
#include <hip/hip_runtime.h>
#include <hip/hip_bf16.h>
#include <hip/hip_fp16.h>

#define HDIM 1024
#define BATCH 64
#define SEQ 2048
#define MTOT (BATCH*SEQ)   // 131072
#define BM 128
#define BN 128
#define BK 64
#define NKT (HDIM/BK)      // 16 k-tiles

typedef float f32x4 __attribute__((ext_vector_type(4)));
typedef _Float16 half8 __attribute__((ext_vector_type(8)));

static __device__ __forceinline__ void gload_lds16(const void* g, void* l) {
  __builtin_amdgcn_global_load_lds((const __attribute__((address_space(1))) void*)g,
                                   (__attribute__((address_space(3))) void*)l, 16, 0, 0);
}

// ---------------- kernel 1: W1 [h][k] fp32 -> W1T [k][h] fp16 ----------------
__global__ void k_w1t(const float* __restrict__ W1, unsigned short* __restrict__ W1T) {
  __shared__ float tile[64][65];
  int h0 = blockIdx.x * 64, k0 = blockIdx.y * 64;
  int t = threadIdx.x;
#pragma unroll
  for (int j = 0; j < 4; ++j) {
    int q = j * 256 + t, r = q >> 4, c = (q & 15) * 4;
    float4 v = *(const float4*)(W1 + (size_t)(h0 + r) * HDIM + k0 + c);
    tile[r][c + 0] = v.x; tile[r][c + 1] = v.y; tile[r][c + 2] = v.z; tile[r][c + 3] = v.w;
  }
  __syncthreads();
#pragma unroll
  for (int j = 0; j < 4; ++j) {
    int q = j * 256 + t, r = q >> 4, c = (q & 15) * 4;
    union { _Float16 h[4]; ushort4 u; } cv;
    cv.h[0] = (_Float16)tile[c + 0][r];
    cv.h[1] = (_Float16)tile[c + 1][r];
    cv.h[2] = (_Float16)tile[c + 2][r];
    cv.h[3] = (_Float16)tile[c + 3][r];
    *(ushort4*)(W1T + (size_t)(k0 + r) * HDIM + h0 + c) = cv.u;
  }
}

// ---------------- kernel 2: dec_proj = dh @ W2 + b  (fp32) ----------------
__global__ void k_decproj(const float* __restrict__ dh, const float* __restrict__ W2,
                          const float* __restrict__ W2b, float* __restrict__ dp) {
  __shared__ float drow[HDIM];
  int b = blockIdx.x, t = threadIdx.x;
#pragma unroll
  for (int j = 0; j < 4; ++j) drow[j * 256 + t] = dh[(size_t)b * HDIM + j * 256 + t];
  __syncthreads();
  f32x4 acc = {0.f, 0.f, 0.f, 0.f};
#pragma unroll 16
  for (int h = 0; h < HDIM; ++h) {
    float d = drow[h];
    f32x4 w = *(const f32x4*)(W2 + (size_t)h * HDIM + t * 4);
    acc += w * d;
  }
  acc += *(const f32x4*)(W2b + t * 4);
  *(f32x4*)(dp + (size_t)b * HDIM + t * 4) = acc;
}

// ---------------- kernel 3: fused GEMM + tanh + v-dot -> score partials ----------------
// A path: global -> regs -> cvt fp16 -> MFMA directly. NO LDS for A (m151: the
// reg->LDS round-trip was the ~650TF ceiling). Wave tile 32 rows x 128 cols
// (acc[2][8]); each wave owns full rows -> epilogue reduces over cols in-wave,
// stores spart directly (no scr LDS, no epilogue barrier).
// B path: R6-verified gload_lds + XOR-swizzle, single Bs buffer, 2 barriers/kt.
// vmcnt(8) at barrier#1 drains only the 4 B gloads (oldest); 8 A-loads ride
// through and are absorbed by the cvt's per-reg waits after the barrier.
__global__ __launch_bounds__(256, 3) void k_scores(
    const float* __restrict__ E, const unsigned short* __restrict__ W1T,
    const float* __restrict__ W1b, const float* __restrict__ dp,
    const float* __restrict__ vw, float* __restrict__ spart) {
  __shared__ __align__(16) unsigned short Bs[BN * BK];   // 16384 B, swizzled

  int t = threadIdx.x;
  // XCD-aware remap: all 8 n-tiles of an m-tile adjacent on one XCD (FETCH 2.1G->0.33G, R2).
  int bid = blockIdx.x;                 // 0..8191
  int xcd = bid & 7;
  int q = bid >> 3;
  int mt = (xcd << 7) + (q >> 3);
  int nt = q & 7;
  int m0 = mt * BM, n0 = nt * BN;
  int b = m0 >> 11;

  int lane = t & 63, wid = t >> 6;      // wave wid owns rows wid*32 .. wid*32+31
  int l15 = lane & 15, l4 = lane >> 4;

  f32x4 acc[2][8];
#pragma unroll
  for (int i = 0; i < 2; ++i)
#pragma unroll
    for (int j = 0; j < 8; ++j) acc[i][j] = {0.f, 0.f, 0.f, 0.f};

  // Per-lane A base: row = m0 + wid*32 + l15 (mi adds 16 rows), col base l4*8 fp32
  const float* Abase = E + (size_t)(m0 + wid * 32 + l15) * HDIM + l4 * 8;

  // B staging coords (4 chunks of 1KB per wave, pre-swizzled source)
  int brow_in = lane >> 3;
  int bu = (lane & 7) ^ brow_in;

  for (int kt = 0; kt < NKT; ++kt) {
    // (1) issue B(kt): 4 gload_lds per wave (these must be the OLDEST vmem)
#pragma unroll
    for (int j = 0; j < 4; ++j) {
      int chunk = wid * 4 + j;
      int row = chunk * 8 + brow_in;
      const unsigned short* g = W1T + (size_t)(n0 + row) * HDIM + kt * BK + bu * 8;
      gload_lds16(g, (char*)Bs + (size_t)chunk * 1024);
    }
    __builtin_amdgcn_sched_barrier(0);   // pin VMEM issue order: B before A

    // (2) issue A(kt) fragment loads -> regs (8 float4/lane):
    //     frag(mi,ks) = rows (wid*32+mi*16+l15), cols kt*64+ks*32+l4*8 .. +8
    float4 areg[8];
#pragma unroll
    for (int mi = 0; mi < 2; ++mi)
#pragma unroll
      for (int ks = 0; ks < 2; ++ks)
#pragma unroll
        for (int p = 0; p < 2; ++p)
          areg[(mi * 2 + ks) * 2 + p] =
              *(const float4*)(Abase + (size_t)mi * 16 * HDIM + kt * 64 + ks * 32 + p * 4);

    // (3) barrier #1: drain the 4 B gloads only (vmcnt 12 -> 8); A rides through
    asm volatile("s_waitcnt vmcnt(8)\n\ts_barrier" ::: "memory");
    __builtin_amdgcn_sched_barrier(0);

    // (4) cvt A -> fp16 frags (compiler inserts counted vmcnt waits per areg)
    half8 af[4];
#pragma unroll
    for (int f = 0; f < 4; ++f) {
      union { _Float16 h[8]; half8 v; } cv;
      float4 x = areg[f * 2], y = areg[f * 2 + 1];
      cv.h[0] = (_Float16)x.x; cv.h[1] = (_Float16)x.y;
      cv.h[2] = (_Float16)x.z; cv.h[3] = (_Float16)x.w;
      cv.h[4] = (_Float16)y.x; cv.h[5] = (_Float16)y.y;
      cv.h[6] = (_Float16)y.z; cv.h[7] = (_Float16)y.w;
      af[f] = cv.v;
    }

    // (5) MFMA: 2 ks x 8 ni x 2 mi = 32; bf read per ni (swizzled, 0-conflict)
    __builtin_amdgcn_s_setprio(1);
#pragma unroll
    for (int ks = 0; ks < 2; ++ks)
#pragma unroll
      for (int ni = 0; ni < 8; ++ni) {
        int row = ni * 16 + l15;
        half8 bf = *(const half8*)((const char*)Bs + row * 128 +
                                   (((ks * 4 + l4) ^ (row & 7)) << 4));
#pragma unroll
        for (int mi = 0; mi < 2; ++mi)
          acc[mi][ni] = __builtin_amdgcn_mfma_f32_16x16x32_f16(af[mi * 2 + ks], bf, acc[mi][ni], 0, 0, 0);
      }
    __builtin_amdgcn_s_setprio(0);

    // (6) barrier #2: all Bs reads done before next kt's gload overwrites
    asm volatile("s_waitcnt lgkmcnt(0)\n\ts_barrier" ::: "memory");
  }

  // epilogue: bias + tanh + v-dot; reduce over 16 cols (l15 lanes); direct store.
  float bias_l[8], v_l[8];
#pragma unroll
  for (int ni = 0; ni < 8; ++ni) {
    int k = n0 + ni * 16 + l15;
    bias_l[ni] = W1b[k] + dp[(size_t)b * HDIM + k];
    v_l[ni] = vw[k];
  }
#pragma unroll
  for (int mi = 0; mi < 2; ++mi) {
#pragma unroll
    for (int r = 0; r < 4; ++r) {
      float s = 0.f;
#pragma unroll
      for (int ni = 0; ni < 8; ++ni) {
        float x = acc[mi][ni][r] + bias_l[ni];
        float ex = __expf(2.f * x);
        float th = 1.f - 2.f / (ex + 1.f);
        s += th * v_l[ni];
      }
      s += __shfl_xor(s, 1); s += __shfl_xor(s, 2);
      s += __shfl_xor(s, 4); s += __shfl_xor(s, 8);
      if (l15 == 0) {
        int row = wid * 32 + mi * 16 + l4 * 4 + r;
        spart[((size_t)m0 + row) * 8 + nt] = s;
      }
    }
  }
}

// ---------------- kernel 4: softmax over S per batch ----------------
__global__ void k_softmax(const float* __restrict__ spart, float* __restrict__ attn) {
  __shared__ float sc[SEQ];
  __shared__ float red[8];
  int b = blockIdx.x, t = threadIdx.x;
  float mx = -1e30f;
#pragma unroll
  for (int j = 0; j < 8; ++j) {
    int s = j * 256 + t;
    const f32x4* p = (const f32x4*)(spart + ((size_t)b * SEQ + s) * 8);
    f32x4 x = p[0], y = p[1];
    float v = (x[0] + x[1]) + (x[2] + x[3]) + (y[0] + y[1]) + (y[2] + y[3]);
    sc[s] = v;
    mx = fmaxf(mx, v);
  }
  for (int m = 1; m < 64; m <<= 1) mx = fmaxf(mx, __shfl_xor(mx, m));
  if ((t & 63) == 0) red[t >> 6] = mx;
  __syncthreads();
  mx = fmaxf(fmaxf(red[0], red[1]), fmaxf(red[2], red[3]));
  float w[8]; float sum = 0.f;
#pragma unroll
  for (int j = 0; j < 8; ++j) {
    float e = __expf(sc[j * 256 + t] - mx);
    w[j] = e; sum += e;
  }
  for (int m = 1; m < 64; m <<= 1) sum += __shfl_xor(sum, m);
  if ((t & 63) == 0) red[4 + (t >> 6)] = sum;
  __syncthreads();
  float inv = 1.f / (red[4] + red[5] + red[6] + red[7]);
#pragma unroll
  for (int j = 0; j < 8; ++j)
    attn[(size_t)b * SEQ + j * 256 + t] = w[j] * inv;
}

// ---------------- kernel 5: context partials over s-chunks ----------------
__global__ void k_ctx_part(const float* __restrict__ E, const float* __restrict__ attn,
                           float* __restrict__ cpart, int rpc) {
  int b = blockIdx.y, ch = blockIdx.x, nch = gridDim.x;
  int t = threadIdx.x;
  const float* wrow = attn + (size_t)b * SEQ + (size_t)ch * rpc;
  const float* Eb = E + ((size_t)b * SEQ + (size_t)ch * rpc) * HDIM;
  f32x4 acc = {0.f, 0.f, 0.f, 0.f};
#pragma unroll 4
  for (int s = 0; s < rpc; ++s) {
    float w = wrow[s];
    f32x4 e = *(const f32x4*)(Eb + (size_t)s * HDIM + t * 4);
    acc += e * w;
  }
  *(f32x4*)(cpart + ((size_t)b * nch + ch) * HDIM + t * 4) = acc;
}

// ---------------- kernel 6: reduce context partials ----------------
__global__ void k_ctx_reduce(const float* __restrict__ cpart, float* __restrict__ ctx, int nch) {
  int idx = blockIdx.x * 256 + threadIdx.x;  // 0..65535
  int b = idx >> 10, k = idx & 1023;
  float s = 0.f;
  for (int c = 0; c < nch; ++c) s += cpart[((size_t)(b * nch + c)) * HDIM + k];
  ctx[idx] = s;
}

extern "C" void kernel_launch(void* const* d_in, const int* in_sizes, int n_in,
                              void* d_out, int out_size, void* d_ws, size_t ws_size,
                              hipStream_t stream) {
  const float* dh  = (const float*)d_in[0];
  const float* E   = (const float*)d_in[1];
  const float* W1w = (const float*)d_in[2];
  const float* W1b = (const float*)d_in[3];
  const float* W2w = (const float*)d_in[4];
  const float* W2b = (const float*)d_in[5];
  const float* vw  = (const float*)d_in[6];
  float* out  = (float*)d_out;
  float* ctx  = out;                 // [64,1024]
  float* attn = out + BATCH * HDIM;  // [64,2048]

  char* ws = (char*)d_ws;
  unsigned short* W1T = (unsigned short*)ws;                 // 2 MB
  float* dp    = (float*)(ws + (2u << 20));                  // 256 KB
  float* spart = (float*)(ws + (2u << 20) + (256u << 10));   // 4 MB
  float* cpart = (float*)(ws + (6u << 20) + (256u << 10));   // up to 8 MB

  size_t need32 = (6u << 20) + (256u << 10) + (size_t)BATCH * 32 * HDIM * 4;
  int nch = (ws_size >= need32) ? 32 : 16;
  int rpc = SEQ / nch;

  k_w1t<<<dim3(16, 16), 256, 0, stream>>>(W1w, W1T);
  k_decproj<<<BATCH, 256, 0, stream>>>(dh, W2w, W2b, dp);
  k_scores<<<(MTOT / BM) * (HDIM / BN), 256, 0, stream>>>(E, W1T, W1b, dp, vw, spart);
  k_softmax<<<BATCH, 256, 0, stream>>>(spart, attn);
  k_ctx_part<<<dim3(nch, BATCH), 256, 0, stream>>>(E, attn, cpart, rpc);
  k_ctx_reduce<<<256, 256, 0, stream>>>(cpart, ctx, nch);
}

// Round 10
// 680.646 us; speedup vs baseline: 4.7853x; 1.7368x over previous
//
#include <hip/hip_runtime.h>
#include <hip/hip_bf16.h>
#include <hip/hip_fp16.h>

#define HDIM 1024
#define BATCH 64
#define SEQ 2048
#define MTOT (BATCH*SEQ)   // 131072
#define BM 128
#define BN 128
#define BK 64
#define NKT (HDIM/BK)      // 16 k-tiles

typedef float f32x4 __attribute__((ext_vector_type(4)));
typedef _Float16 half8 __attribute__((ext_vector_type(8)));

static __device__ __forceinline__ void gload_lds16(const void* g, void* l) {
  __builtin_amdgcn_global_load_lds((const __attribute__((address_space(1))) void*)g,
                                   (__attribute__((address_space(3))) void*)l, 16, 0, 0);
}

// ---------------- kernel 1: W1 [h][k] fp32 -> W1T [k][h] fp16 ----------------
__global__ void k_w1t(const float* __restrict__ W1, unsigned short* __restrict__ W1T) {
  __shared__ float tile[64][65];
  int h0 = blockIdx.x * 64, k0 = blockIdx.y * 64;
  int t = threadIdx.x;
#pragma unroll
  for (int j = 0; j < 4; ++j) {
    int q = j * 256 + t, r = q >> 4, c = (q & 15) * 4;
    float4 v = *(const float4*)(W1 + (size_t)(h0 + r) * HDIM + k0 + c);
    tile[r][c + 0] = v.x; tile[r][c + 1] = v.y; tile[r][c + 2] = v.z; tile[r][c + 3] = v.w;
  }
  __syncthreads();
#pragma unroll
  for (int j = 0; j < 4; ++j) {
    int q = j * 256 + t, r = q >> 4, c = (q & 15) * 4;
    union { _Float16 h[4]; ushort4 u; } cv;
    cv.h[0] = (_Float16)tile[c + 0][r];
    cv.h[1] = (_Float16)tile[c + 1][r];
    cv.h[2] = (_Float16)tile[c + 2][r];
    cv.h[3] = (_Float16)tile[c + 3][r];
    *(ushort4*)(W1T + (size_t)(k0 + r) * HDIM + h0 + c) = cv.u;
  }
}

// ---------------- kernel 2: dec_proj = dh @ W2 + b  (fp32) ----------------
__global__ void k_decproj(const float* __restrict__ dh, const float* __restrict__ W2,
                          const float* __restrict__ W2b, float* __restrict__ dp) {
  __shared__ float drow[HDIM];
  int b = blockIdx.x, t = threadIdx.x;
#pragma unroll
  for (int j = 0; j < 4; ++j) drow[j * 256 + t] = dh[(size_t)b * HDIM + j * 256 + t];
  __syncthreads();
  f32x4 acc = {0.f, 0.f, 0.f, 0.f};
#pragma unroll 16
  for (int h = 0; h < HDIM; ++h) {
    float d = drow[h];
    f32x4 w = *(const f32x4*)(W2 + (size_t)h * HDIM + t * 4);
    acc += w * d;
  }
  acc += *(const f32x4*)(W2b + t * 4);
  *(f32x4*)(dp + (size_t)b * HDIM + t * 4) = acc;
}

// ---------------- kernel 3: fused GEMM + tanh + v-dot -> score partials ----------------
// Deep pipeline (T3/T4 reduction to 4-wave 128x128): ONE barrier per K-tile,
// counted vmcnt(12) (= the 12 vmem of phase t-1) -- never drains in-flight
// prefetch. Rotation: B in 3 buffers (stage t+2 issued right after the barrier
// that ends its readers' phase = race-free by issue order); A in 2 buffers
// (explicit ds_write in phase t targets the buffer read in t+1, whose previous
// readers finished at this phase's barrier). A: reg-prefetch + cvt fp16 (R6-
// verified); B: gload_lds pre-swizzled source (R6-verified, 0 conflicts).
// LDS = 2*16K(A) + 3*16K(B) = 81920 B -> exactly 2 blocks/CU.
__global__ __launch_bounds__(256, 2) void k_scores(
    const float* __restrict__ E, const unsigned short* __restrict__ W1T,
    const float* __restrict__ W1b, const float* __restrict__ dp,
    const float* __restrict__ vw, float* __restrict__ spart) {
  __shared__ __align__(16) _Float16 Ab[2][BM * BK];        // 32 KB
  __shared__ __align__(16) unsigned short Bb[3][BN * BK];  // 48 KB
  float (*scr)[2] = (float(*)[2])Bb[0];   // epilogue alias (post-loop barrier; no DMA targets Bb[0] late)

  int t = threadIdx.x;
  // XCD-aware remap: all 8 n-tiles of an m-tile adjacent on one XCD (FETCH 2.1G->0.33G, R2).
  int bid = blockIdx.x;                 // 0..8191
  int xcd = bid & 7;
  int q = bid >> 3;
  int mt = (xcd << 7) + (q >> 3);
  int nt = q & 7;
  int m0 = mt * BM, n0 = nt * BN;
  int b = m0 >> 11;

  int lane = t & 63, wid = t >> 6;
  int wr = wid >> 1, wc = wid & 1;
  int l15 = lane & 15, l4 = lane >> 4;

  // bias + v in registers (R8-verified piece)
  float bias_l[4], v_l[4];
#pragma unroll
  for (int ni = 0; ni < 4; ++ni) {
    int k = n0 + wc * 64 + ni * 16 + l15;
    bias_l[ni] = W1b[k] + dp[(size_t)b * HDIM + k];
    v_l[ni] = vw[k];
  }

  f32x4 acc[4][4];
#pragma unroll
  for (int i = 0; i < 4; ++i)
#pragma unroll
    for (int j = 0; j < 4; ++j) acc[i][j] = {0.f, 0.f, 0.f, 0.f};

  // A staging coords (coalesced): rows j*16+ar, fp32 cols ac..ac+3
  int ar = t >> 4;                       // 0..15
  int ac = (t & 15) * 4;                 // 0..60
  int aswz = (((ac >> 3) ^ (ar & 7)) << 4) + ((ac & 7) << 1);
  const float* Abase = E + (size_t)m0 * HDIM;

  // ---- prologue: B(0)->Bb[0], B(1)->Bb[1]; A(0)->regs->Ab[0]; A(1)->regs
#pragma unroll
  for (int j = 0; j < 4; ++j) {
    int chunk = wid * 4 + j;
    int row = chunk * 8 + (lane >> 3);
    int u = (lane & 7) ^ (lane >> 3);
    gload_lds16(W1T + (size_t)(n0 + row) * HDIM + u * 8, (char*)Bb[0] + (size_t)chunk * 1024);
  }
#pragma unroll
  for (int j = 0; j < 4; ++j) {
    int chunk = wid * 4 + j;
    int row = chunk * 8 + (lane >> 3);
    int u = (lane & 7) ^ (lane >> 3);
    gload_lds16(W1T + (size_t)(n0 + row) * HDIM + BK + u * 8, (char*)Bb[1] + (size_t)chunk * 1024);
  }
  float4 areg[8];
#pragma unroll
  for (int j = 0; j < 8; ++j)
    areg[j] = *(const float4*)(Abase + (size_t)(j * 16 + ar) * HDIM + ac);
#pragma unroll
  for (int j = 0; j < 8; ++j) {
    union { _Float16 h[4]; unsigned long long u64; } cv;
    cv.h[0] = (_Float16)areg[j].x; cv.h[1] = (_Float16)areg[j].y;
    cv.h[2] = (_Float16)areg[j].z; cv.h[3] = (_Float16)areg[j].w;
    *(unsigned long long*)((char*)Ab[0] + (j * 16 + ar) * 128 + aswz) = cv.u64;
  }
#pragma unroll
  for (int j = 0; j < 8; ++j)
    areg[j] = *(const float4*)(Abase + (size_t)(j * 16 + ar) * HDIM + BK + ac);

  for (int kt = 0; kt < NKT; ++kt) {
    // one barrier per K-tile; vmcnt(12) = phase(t-1)'s 12 vmem stay in flight,
    // everything older (incl. B(t)) is retired. lgkm drains A ds_writes.
    asm volatile("s_waitcnt vmcnt(12) lgkmcnt(0)\n\ts_barrier" ::: "memory");
    __builtin_amdgcn_sched_barrier(0);

    // stage B(kt+2) -> Bb[(kt+2)%3]: readers finished at the barrier above; DMA
    // overlaps the MFMA below and retires at the kt+2 barrier's vmcnt.
    {
      int ktb = ((kt + 2) & (NKT - 1)) * BK;
      char* bdst = (char*)Bb[(kt + 2) % 3];
#pragma unroll
      for (int j = 0; j < 4; ++j) {
        int chunk = wid * 4 + j;
        int row = chunk * 8 + (lane >> 3);
        int u = (lane & 7) ^ (lane >> 3);
        gload_lds16(W1T + (size_t)(n0 + row) * HDIM + ktb + u * 8, bdst + (size_t)chunk * 1024);
      }
    }

    // MFMA on Ab[kt&1], Bb[kt%3] (swizzled reads, 0 conflicts)
    const char* Ac = (const char*)Ab[kt & 1];
    const char* Bc = (const char*)Bb[kt % 3];
    __builtin_amdgcn_s_setprio(1);
#pragma unroll
    for (int ks = 0; ks < 2; ++ks) {
      half8 af[4], bf[4];
#pragma unroll
      for (int mi = 0; mi < 4; ++mi) {
        int row = wr * 64 + mi * 16 + l15;
        af[mi] = *(const half8*)(Ac + row * 128 + (((ks * 4 + l4) ^ (row & 7)) << 4));
      }
#pragma unroll
      for (int ni = 0; ni < 4; ++ni) {
        int row = wc * 64 + ni * 16 + l15;
        bf[ni] = *(const half8*)(Bc + row * 128 + (((ks * 4 + l4) ^ (row & 7)) << 4));
      }
#pragma unroll
      for (int mi = 0; mi < 4; ++mi)
#pragma unroll
        for (int ni = 0; ni < 4; ++ni)
          acc[mi][ni] = __builtin_amdgcn_mfma_f32_16x16x32_f16(af[mi], bf[ni], acc[mi][ni], 0, 0, 0);
    }
    __builtin_amdgcn_s_setprio(0);

    // cvt A(kt+1) regs -> Ab[(kt+1)&1] (that buffer's readers finished last phase;
    // compiler auto-inserts the counted vmcnt wait for areg arrival)
    {
      char* Ad = (char*)Ab[(kt + 1) & 1];
#pragma unroll
      for (int j = 0; j < 8; ++j) {
        union { _Float16 h[4]; unsigned long long u64; } cv;
        cv.h[0] = (_Float16)areg[j].x; cv.h[1] = (_Float16)areg[j].y;
        cv.h[2] = (_Float16)areg[j].z; cv.h[3] = (_Float16)areg[j].w;
        *(unsigned long long*)(Ad + (j * 16 + ar) * 128 + aswz) = cv.u64;
      }
    }
    // issue A(kt+2) -> regs (WAR on areg keeps this after the cvt)
    {
      int kta = ((kt + 2) & (NKT - 1)) * BK;
#pragma unroll
      for (int j = 0; j < 8; ++j)
        areg[j] = *(const float4*)(Abase + (size_t)(j * 16 + ar) * HDIM + kta + ac);
    }
  }

  // drain stray ds ops; all waves past their last reads before scr alias reuse
  asm volatile("s_waitcnt lgkmcnt(0)\n\ts_barrier" ::: "memory");

  // epilogue: bias + tanh + v-dot, 16-lane shuffle reduce, cross-wc via scr(=Bb[0])
#pragma unroll
  for (int mi = 0; mi < 4; ++mi) {
#pragma unroll
    for (int r = 0; r < 4; ++r) {
      float s = 0.f;
#pragma unroll
      for (int ni = 0; ni < 4; ++ni) {
        float x = acc[mi][ni][r] + bias_l[ni];
        float ex = __expf(2.f * x);
        float th = 1.f - 2.f / (ex + 1.f);
        s += th * v_l[ni];
      }
      s += __shfl_xor(s, 1); s += __shfl_xor(s, 2);
      s += __shfl_xor(s, 4); s += __shfl_xor(s, 8);
      if (l15 == 0) scr[wr * 64 + mi * 16 + l4 * 4 + r][wc] = s;
    }
  }
  __syncthreads();
  if (t < BM) spart[((size_t)m0 + t) * 8 + nt] = scr[t][0] + scr[t][1];
}

// ---------------- kernel 4: softmax over S per batch ----------------
__global__ void k_softmax(const float* __restrict__ spart, float* __restrict__ attn) {
  __shared__ float sc[SEQ];
  __shared__ float red[8];
  int b = blockIdx.x, t = threadIdx.x;
  float mx = -1e30f;
#pragma unroll
  for (int j = 0; j < 8; ++j) {
    int s = j * 256 + t;
    const f32x4* p = (const f32x4*)(spart + ((size_t)b * SEQ + s) * 8);
    f32x4 x = p[0], y = p[1];
    float v = (x[0] + x[1]) + (x[2] + x[3]) + (y[0] + y[1]) + (y[2] + y[3]);
    sc[s] = v;
    mx = fmaxf(mx, v);
  }
  for (int m = 1; m < 64; m <<= 1) mx = fmaxf(mx, __shfl_xor(mx, m));
  if ((t & 63) == 0) red[t >> 6] = mx;
  __syncthreads();
  mx = fmaxf(fmaxf(red[0], red[1]), fmaxf(red[2], red[3]));
  float w[8]; float sum = 0.f;
#pragma unroll
  for (int j = 0; j < 8; ++j) {
    float e = __expf(sc[j * 256 + t] - mx);
    w[j] = e; sum += e;
  }
  for (int m = 1; m < 64; m <<= 1) sum += __shfl_xor(sum, m);
  if ((t & 63) == 0) red[4 + (t >> 6)] = sum;
  __syncthreads();
  float inv = 1.f / (red[4] + red[5] + red[6] + red[7]);
#pragma unroll
  for (int j = 0; j < 8; ++j)
    attn[(size_t)b * SEQ + j * 256 + t] = w[j] * inv;
}

// ---------------- kernel 5: context partials over s-chunks ----------------
__global__ void k_ctx_part(const float* __restrict__ E, const float* __restrict__ attn,
                           float* __restrict__ cpart, int rpc) {
  int b = blockIdx.y, ch = blockIdx.x, nch = gridDim.x;
  int t = threadIdx.x;
  const float* wrow = attn + (size_t)b * SEQ + (size_t)ch * rpc;
  const float* Eb = E + ((size_t)b * SEQ + (size_t)ch * rpc) * HDIM;
  f32x4 acc = {0.f, 0.f, 0.f, 0.f};
#pragma unroll 4
  for (int s = 0; s < rpc; ++s) {
    float w = wrow[s];
    f32x4 e = *(const f32x4*)(Eb + (size_t)s * HDIM + t * 4);
    acc += e * w;
  }
  *(f32x4*)(cpart + ((size_t)b * nch + ch) * HDIM + t * 4) = acc;
}

// ---------------- kernel 6: reduce context partials ----------------
__global__ void k_ctx_reduce(const float* __restrict__ cpart, float* __restrict__ ctx, int nch) {
  int idx = blockIdx.x * 256 + threadIdx.x;  // 0..65535
  int b = idx >> 10, k = idx & 1023;
  float s = 0.f;
  for (int c = 0; c < nch; ++c) s += cpart[((size_t)(b * nch + c)) * HDIM + k];
  ctx[idx] = s;
}

extern "C" void kernel_launch(void* const* d_in, const int* in_sizes, int n_in,
                              void* d_out, int out_size, void* d_ws, size_t ws_size,
                              hipStream_t stream) {
  const float* dh  = (const float*)d_in[0];
  const float* E   = (const float*)d_in[1];
  const float* W1w = (const float*)d_in[2];
  const float* W1b = (const float*)d_in[3];
  const float* W2w = (const float*)d_in[4];
  const float* W2b = (const float*)d_in[5];
  const float* vw  = (const float*)d_in[6];
  float* out  = (float*)d_out;
  float* ctx  = out;                 // [64,1024]
  float* attn = out + BATCH * HDIM;  // [64,2048]

  char* ws = (char*)d_ws;
  unsigned short* W1T = (unsigned short*)ws;                 // 2 MB
  float* dp    = (float*)(ws + (2u << 20));                  // 256 KB
  float* spart = (float*)(ws + (2u << 20) + (256u << 10));   // 4 MB
  float* cpart = (float*)(ws + (6u << 20) + (256u << 10));   // up to 8 MB

  size_t need32 = (6u << 20) + (256u << 10) + (size_t)BATCH * 32 * HDIM * 4;
  int nch = (ws_size >= need32) ? 32 : 16;
  int rpc = SEQ / nch;

  k_w1t<<<dim3(16, 16), 256, 0, stream>>>(W1w, W1T);
  k_decproj<<<BATCH, 256, 0, stream>>>(dh, W2w, W2b, dp);
  k_scores<<<(MTOT / BM) * (HDIM / BN), 256, 0, stream>>>(E, W1T, W1b, dp, vw, spart);
  k_softmax<<<BATCH, 256, 0, stream>>>(spart, attn);
  k_ctx_part<<<dim3(nch, BATCH), 256, 0, stream>>>(E, attn, cpart, rpc);
  k_ctx_reduce<<<256, 256, 0, stream>>>(cpart, ctx, nch);
}